// Round 7
// baseline (103.387 us; speedup 1.0000x reference)
//
#include <hip/hip_runtime.h>
#include <hip/hip_bf16.h>
#include <math.h>

// PhaseMLP fused, R10: R6 structure + conflict-free B LDS permutation.
//   y[b,o] = sum_k c_k(b) * ( x[b,:] @ W_k + b_k )
// Evidence across R4-R9: reg-direct B always ~40-42us; gl_lds-staged always
// ~28-30us regardless of depth/order/decorrelation. Diagnosis: R6's LOADB
// (bOff = col*64+quad*16) is a structural 4-way LDS bank conflict (only 8
// of 32 banks per 16-lane phase) -> ~14us of the 28us on the LDS port.
// Fix (both-sides permutation, zero cost): write-lane w of each gl_lds
// fetches (col=w&15, koff=(w>>4)*8) so the fragment for MFMA-lane
// (col=lane&15, quad=lane>>4) lands at byte lane*16 -> LOADB is a dense
// 1024B wave sweep (conflict-free). Same instruction count, same 16x64B
// L2 lines per gl_lds. Skeleton = R6 (measured best): VMW4 -> ds_read ->
// LGKM0 -> STAGE -> MFMA, raw barriers keep the stream live across layers.
// Bias folded into acc init (R9, verified); Catmull in regs (R7);
// k_wt_all 128x1024 (R9).

typedef __attribute__((ext_vector_type(8))) short bf16x8;
typedef __attribute__((ext_vector_type(4))) float f32x4;

// LDS layout (bytes)
#define LDS_A0 0                    // 16 rows x 256B  = 4096
#define LDS_A1 4096                 // 16 rows x 512B  = 8192
#define LDS_A2 12288                // 16 rows x 512B  = 8192
#define LDS_B  20480                // 16 waves x 2 slots x 4096 = 131072
#define LDS_TOT (20480 + 131072)    // 151552 < 160K

#define VMW4()  asm volatile("s_waitcnt vmcnt(4)" ::: "memory")
#define VMW0()  asm volatile("s_waitcnt vmcnt(0)" ::: "memory")
#define LGKM0() asm volatile("s_waitcnt lgkmcnt(0)" ::: "memory")

static __device__ __forceinline__ void bar_keep_vmcnt() {
  asm volatile("s_waitcnt lgkmcnt(0)" ::: "memory");
  __builtin_amdgcn_s_barrier();
  asm volatile("" ::: "memory");
}

typedef const __attribute__((address_space(1))) unsigned char* gp1_t;
typedef __attribute__((address_space(3))) unsigned char* lp3_t;
static __device__ __forceinline__ void gl_lds16(const void* g, void* l) {
  __builtin_amdgcn_global_load_lds((gp1_t)g, (lp3_t)l, 16, 0, 0);
}

// stage one K=32 chunk (4 anchors x 1KB) of this wave's 16 columns.
// sb = per-lane source base: Wt + (colbase + (lane&15))*ROWLEN + (lane>>4)*8
// -> write-lane w's 16B lands at dst byte w*16, which is exactly the
//    B-fragment MFMA-lane w needs: LDS chunk = [anchor][lane*16].
#define STAGE(sb, KIN, ci, slot) do {                                  \
    const unsigned short* _s = (sb) + (ci) * 32;                       \
    char* _d = myB + (slot) * 4096;                                    \
    gl_lds16(_s,             _d);                                      \
    gl_lds16(_s + (KIN),     _d + 1024);                               \
    gl_lds16(_s + 2 * (KIN), _d + 2048);                               \
    gl_lds16(_s + 3 * (KIN), _d + 3072);                               \
  } while (0)

static __device__ __forceinline__ unsigned short f2bf(float f) {
  union { float f; unsigned int u; } v; v.f = f;
  unsigned int r = v.u + 0x7fffu + ((v.u >> 16) & 1u);  // RNE
  return (unsigned short)(r >> 16);
}

// Catmull-Rom basis coeffs in ABSOLUTE anchor order (c[0..3] for anchors 0..3)
static __device__ __forceinline__ void catmull(float ph, float c[4]) {
  float t = 4.0f * ph;
  float ft = floorf(t);
  int i1 = ((int)ft) & 3;
  float w = t - ft;
  float w2 = w * w, w3 = w2 * w;
  float r0 = -0.5f * w + w2 - 0.5f * w3;
  float r1 = 1.0f - 2.5f * w2 + 1.5f * w3;
  float r2 = 0.5f * w + 2.0f * w2 - 1.5f * w3;
  float r3 = -0.5f * w2 + 0.5f * w3;
  c[(i1 + 3) & 3] = r0;
  c[i1]           = r1;
  c[(i1 + 1) & 3] = r2;
  c[(i1 + 2) & 3] = r3;
}

// ---------------------------------------------------------------------------
// Prep: transpose+convert all three weight tensors (fp32 [4K,O] -> bf16 [O,4K])
// 128 blocks x (32,32): 4 tile-teams of (32,8) per block, 512 tiles total.
// ---------------------------------------------------------------------------
__global__ __launch_bounds__(1024) void k_wt_all(
    const float* __restrict__ w0, const float* __restrict__ w1,
    const float* __restrict__ w2, unsigned short* __restrict__ t0,
    unsigned short* __restrict__ t1, unsigned short* __restrict__ t2) {
  __shared__ float tile[4][32][33];
  const int team = threadIdx.y >> 3;      // 0..3
  const int tyy = threadIdx.y & 7;        // 0..7
  const int tx = threadIdx.x;             // 0..31
  const int bid = blockIdx.x * 4 + team;  // 0..511
  const float* W; unsigned short* T; int R, C, idx;
  if (bid < 128)      { W = w0; T = t0; R = 512;  C = 256; idx = bid; }
  else if (bid < 384) { W = w1; T = t1; R = 1024; C = 256; idx = bid - 128; }
  else                { W = w2; T = t2; R = 1024; C = 128; idx = bid - 384; }
  const int ntc = C >> 5;
  const int tr = (idx / ntc) << 5;
  const int tc = (idx % ntc) << 5;
#pragma unroll
  for (int j = tyy; j < 32; j += 8)
    tile[team][j][tx] = W[(size_t)(tr + j) * C + (tc + tx)];
  __syncthreads();
#pragma unroll
  for (int j = tyy; j < 32; j += 8)
    T[(size_t)(tc + j) * R + (tr + tx)] = f2bf(tile[team][tx][j]);
}

// mid-layer epilogue: anchor-combine (bias already in acc) + ELU + bf16 write
static __device__ __forceinline__ void epi_mid(f32x4 a0, f32x4 a1, f32x4 a2,
                                               f32x4 a3, const float cbr[4][4],
                                               int colg, int quad, char* outBuf) {
  const int g = colg >> 3;
  const int j2 = (colg & 7) * 2;
#pragma unroll
  for (int r = 0; r < 4; ++r) {
    const int m = quad * 4 + r;
    float y = cbr[r][0] * a0[r] + cbr[r][1] * a1[r] +
              cbr[r][2] * a2[r] + cbr[r][3] * a3[r];
    float a = y > 0.0f ? y : (__expf(y) - 1.0f);  // ELU
    *(unsigned short*)(outBuf + m * 512 + (((g ^ (m & 15)) << 4) + j2)) = f2bf(a);
  }
}

#define MFMA4()                                                            \
  acc0 = __builtin_amdgcn_mfma_f32_16x16x32_bf16(av, bv0, acc0, 0, 0, 0);  \
  acc1 = __builtin_amdgcn_mfma_f32_16x16x32_bf16(av, bv1, acc1, 0, 0, 0);  \
  acc2 = __builtin_amdgcn_mfma_f32_16x16x32_bf16(av, bv2, acc2, 0, 0, 0);  \
  acc3 = __builtin_amdgcn_mfma_f32_16x16x32_bf16(av, bv3, acc3, 0, 0, 0)

// dense conflict-free chunk read: lane l reads byte l*16 of each anchor KB
#define LOADB()                                                \
  bf16x8 bv0 = *(const bf16x8*)(bs + bOff);                    \
  bf16x8 bv1 = *(const bf16x8*)(bs + 1024 + bOff);             \
  bf16x8 bv2 = *(const bf16x8*)(bs + 2048 + bOff);             \
  bf16x8 bv3 = *(const bf16x8*)(bs + 3072 + bOff)

__global__ __launch_bounds__(1024, 4) void k_fused(
    const float* __restrict__ x, const float* __restrict__ phase,
    const unsigned short* __restrict__ Wt0, const float* __restrict__ b0,
    const unsigned short* __restrict__ Wt1, const float* __restrict__ b1,
    const unsigned short* __restrict__ Wt2, const float* __restrict__ b2,
    float* __restrict__ out) {
  __shared__ __align__(1024) char smem[LDS_TOT];

  const int tid = threadIdx.x;
  const int lane = tid & 63;
  const int wid = tid >> 6;     // 0..15
  const int col = lane & 15;    // MFMA row-of-A / col-of-B lane index
  const int quad = lane >> 4;
  const int m0 = blockIdx.x * 16;
  const int colg = wid * 16 + col;           // L0/L1 output column
  const int cg = wid & 7, kh = wid >> 3;     // L2: col-group + K-half
  const int colg2 = cg * 16 + col;
  const int hi16 = (col & 12) << 4;          // A-swizzle high bits
  const int lb = (quad ^ (col & 3)) << 4;    // A-swizzle low bits
  const int bOff = lane * 16;                // dense B chunk read (no conflict)

  char* myB = smem + LDS_B + wid * 8192;

  // per-lane staged-source bases: write-lane w fetches (col=w&15, koff=(w>>4)*8)
  const unsigned short* sb0 = Wt0 + (size_t)(wid * 16 + col) * 512 + quad * 8;
  const unsigned short* sb1 = Wt1 + (size_t)(wid * 16 + col) * 1024 + quad * 8;
  const unsigned short* sb2 = Wt2 + (size_t)(cg * 16 + col) * 1024 + kh * 128 + quad * 8;

  // ---- prologue loads: biases, phases, x — all consumed BEFORE the K-loops
  float4 xv = {0.f, 0.f, 0.f, 0.f};
  if (tid < 512)
    xv = *(const float4*)(x + (size_t)(m0 + (tid >> 5)) * 128 + (tid & 31) * 4);

  float bva[4], bvb[4], bvc[4];
#pragma unroll
  for (int k = 0; k < 4; ++k) {
    bva[k] = b0[k * 256 + colg];
    bvb[k] = b1[k * 256 + colg];
    bvc[k] = b2[k * 128 + colg2];
  }
  float ph[4];
#pragma unroll
  for (int r = 0; r < 4; ++r) ph[r] = phase[m0 + quad * 4 + r];

  // ---- start the weight stream (chunks 0,1 -> slots 0,1) ----
  STAGE(sb0, 128, 0, 0);
  STAGE(sb0, 128, 1, 1);

  // per-lane Catmull coeffs for its 4 rows
  float cbr[4][4];
#pragma unroll
  for (int r = 0; r < 4; ++r) catmull(ph[r], cbr[r]);

  // ---- build A0: unscaled bf16 x, granule-swizzled (g ^ (row&15)) ----
  if (tid < 512) {
    const int row = tid >> 5, seg = tid & 31;
    const int g = seg >> 1, h = seg & 1;
    short4 hv;
    hv.x = (short)f2bf(xv.x); hv.y = (short)f2bf(xv.y);
    hv.z = (short)f2bf(xv.z); hv.w = (short)f2bf(xv.w);
    *(short4*)(smem + LDS_A0 + row * 256 + ((g ^ (row & 15)) << 4) + h * 8) = hv;
  }
  bar_keep_vmcnt();

  f32x4 acc0, acc1, acc2, acc3;

  // ---- layer 0: A0 (K=128 x 4 anchors) @ Wt0 -> A1. chunks 0..3 ----
  {
    acc0 = (f32x4){bva[0], bva[0], bva[0], bva[0]};
    acc1 = (f32x4){bva[1], bva[1], bva[1], bva[1]};
    acc2 = (f32x4){bva[2], bva[2], bva[2], bva[2]};
    acc3 = (f32x4){bva[3], bva[3], bva[3], bva[3]};
    const char* aL = smem + LDS_A0 + col * 256 + lb;
#pragma unroll
    for (int i = 0; i < 4; ++i) {
      VMW4();                                           // chunk i landed
      const char* bs = myB + (i & 1) * 4096;
      bf16x8 av = *(const bf16x8*)(aL + ((i << 6) ^ hi16));
      LOADB();
      LGKM0();                       // slot reads in regs -> safe to overwrite
      if (i == 0)      STAGE(sb0, 128, 2, 0);
      else if (i == 1) STAGE(sb0, 128, 3, 1);
      else if (i == 2) STAGE(sb1, 256, 0, 0);   // cross-layer prefetch
      else             STAGE(sb1, 256, 1, 1);
      MFMA4();
    }
    epi_mid(acc0, acc1, acc2, acc3, cbr, colg, quad, smem + LDS_A1);
  }
  bar_keep_vmcnt();

  // ---- layer 1: A1 (K=256 x 4 anchors) @ Wt1 -> A2. chunks 4..11 ----
  {
    acc0 = (f32x4){bvb[0], bvb[0], bvb[0], bvb[0]};
    acc1 = (f32x4){bvb[1], bvb[1], bvb[1], bvb[1]};
    acc2 = (f32x4){bvb[2], bvb[2], bvb[2], bvb[2]};
    acc3 = (f32x4){bvb[3], bvb[3], bvb[3], bvb[3]};
    const char* aL = smem + LDS_A1 + col * 512 + lb;
#pragma unroll
    for (int i = 0; i < 8; ++i) {
      VMW4();
      const char* bs = myB + (i & 1) * 4096;
      bf16x8 av = *(const bf16x8*)(aL + ((i << 6) ^ hi16));
      LOADB();
      LGKM0();
      if (i < 6)       STAGE(sb1, 256, i + 2, i & 1);
      else if (i == 6) STAGE(sb2, 256, 0, 0);   // cross-layer prefetch
      else             STAGE(sb2, 256, 1, 1);
      MFMA4();
    }
    epi_mid(acc0, acc1, acc2, acc3, cbr, colg, quad, smem + LDS_A2);
  }
  bar_keep_vmcnt();

  // ---- layer 2: A2 (K=256 x 4 anchors) @ Wt2 -> out fp32. chunks 12..15 ----
  {
    const float c0 = kh ? 0.f : bvc[0], c1 = kh ? 0.f : bvc[1];
    const float c2 = kh ? 0.f : bvc[2], c3 = kh ? 0.f : bvc[3];
    acc0 = (f32x4){c0, c0, c0, c0};
    acc1 = (f32x4){c1, c1, c1, c1};
    acc2 = (f32x4){c2, c2, c2, c2};
    acc3 = (f32x4){c3, c3, c3, c3};
    const char* aL = smem + LDS_A2 + col * 512 + kh * 256 + lb;
#pragma unroll
    for (int i = 0; i < 4; ++i) {
      if (i < 3) { VMW4(); } else { VMW0(); }
      const char* bs = myB + (i & 1) * 4096;
      bf16x8 av = *(const bf16x8*)(aL + ((i << 6) ^ hi16));
      LOADB();
      if (i < 2) {
        LGKM0();
        if (i == 0) STAGE(sb2, 256, 2, 0);
        else        STAGE(sb2, 256, 3, 1);
      }
      MFMA4();
    }

    // anchor-combine partials (bias already inside kh==0's acc)
    float part[4];
#pragma unroll
    for (int r = 0; r < 4; ++r)
      part[r] = cbr[r][0] * acc0[r] + cbr[r][1] * acc1[r] +
                cbr[r][2] * acc2[r] + cbr[r][3] * acc3[r];

    // all gl_lds writes landed (VMW0 per wave) -> overlay reduce buf on Bst
    bar_keep_vmcnt();
    float* red = (float*)(smem + LDS_B);   // [8][16][17] = 8704 B
    if (kh) {
#pragma unroll
      for (int r = 0; r < 4; ++r)
        red[cg * 272 + (quad * 4 + r) * 17 + col] = part[r];
    }
    bar_keep_vmcnt();
    if (!kh) {
#pragma unroll
      for (int r = 0; r < 4; ++r) {
        const int m = quad * 4 + r;
        float y = part[r] + red[cg * 272 + m * 17 + col];
        out[(size_t)(m0 + m) * 128 + colg2] = y;
      }
    }
  }
}

// ---------------------------------------------------------------------------
// ws layout: Wt0 @0 (256KB), Wt1 @256KB (512KB), Wt2 @768KB (256KB). 1 MB.
// ---------------------------------------------------------------------------
extern "C" void kernel_launch(void* const* d_in, const int* in_sizes, int n_in,
                              void* d_out, int out_size, void* d_ws, size_t ws_size,
                              hipStream_t stream) {
  const float* x     = (const float*)d_in[0];
  const float* phase = (const float*)d_in[1];
  const float* w0    = (const float*)d_in[2];
  const float* b0    = (const float*)d_in[3];
  const float* w1    = (const float*)d_in[4];
  const float* b1    = (const float*)d_in[5];
  const float* w2    = (const float*)d_in[6];
  const float* b2    = (const float*)d_in[7];
  float* out = (float*)d_out;

  char* ws = (char*)d_ws;
  unsigned short* Wt0 = (unsigned short*)ws;
  unsigned short* Wt1 = (unsigned short*)(ws + 262144);
  unsigned short* Wt2 = (unsigned short*)(ws + 262144 + 524288);

  k_wt_all<<<128, dim3(32, 32), 0, stream>>>(w0, w1, w2, Wt0, Wt1, Wt2);
  k_fused<<<256, 1024, 0, stream>>>(x, phase, Wt0, b0, Wt1, b1, Wt2, b2, out);
}

// Round 8
// 89.752 us; speedup vs baseline: 1.1519x; 1.1519x over previous
//
#include <hip/hip_runtime.h>
#include <hip/hip_bf16.h>
#include <math.h>

// PhaseMLP fused, R11: exact R6 (best: 88.66us) + granule-XOR B swizzle.
//   y[b,o] = sum_k c_k(b) * ( x[b,:] @ W_k + b_k )
// R10 post-mortem: its lane->source remap fixed the LDS read conflict but
// broke global coalescing (quarter-wave: 16x16B scattered vs R6's 4x64B
// merged) -> net -15us. Constraint: gl_lds writes granule w from lane w,
// and coalescing needs 4-lane groups to fetch one row's 64B; any plain row
// permutation leaves the read with p mod 8 in {2 values} per 8-lane phase.
// Fix: XOR involution p' = p ^ ((p>>3)&7) on granule positions:
//  - write side: lane w fetches (row,qs) of p = w ^ ((w>>3)&7). Within each
//    4-lane group the row is constant, quarters XOR-reordered -> same 64B
//    address set, coalescing preserved (HK pre-swizzled-source pattern).
//  - read side: bOff = (p ^ ((p>>3)&7))*16, p = (lane&15)*4 + (lane>>4).
//    p' mod 8 all-distinct per 8-lane phase -> 32 banks -> conflict-free.
// Everything else byte-identical to R6 (single-variable A/B).

typedef __attribute__((ext_vector_type(8))) short bf16x8;
typedef __attribute__((ext_vector_type(4))) float f32x4;

// LDS layout (bytes)
#define LDS_A0 0                    // 16 rows x 256B  = 4096
#define LDS_A1 4096                 // 16 rows x 512B  = 8192
#define LDS_A2 12288                // 16 rows x 512B  = 8192
#define LDS_CB 20480                // 16 x float4     = 256
#define LDS_B  21504                // 16 waves x 2 slots x 4096 = 131072
#define LDS_TOT (21504 + 131072)    // 152576 < 160K

#define VMW4()  asm volatile("s_waitcnt vmcnt(4)" ::: "memory")
#define VMW0()  asm volatile("s_waitcnt vmcnt(0)" ::: "memory")
#define LGKM0() asm volatile("s_waitcnt lgkmcnt(0)" ::: "memory")

static __device__ __forceinline__ void bar_keep_vmcnt() {
  asm volatile("s_waitcnt lgkmcnt(0)" ::: "memory");
  __builtin_amdgcn_s_barrier();
  asm volatile("" ::: "memory");
}

typedef const __attribute__((address_space(1))) unsigned char* gp1_t;
typedef __attribute__((address_space(3))) unsigned char* lp3_t;
static __device__ __forceinline__ void gl_lds16(const void* g, void* l) {
  __builtin_amdgcn_global_load_lds((gp1_t)g, (lp3_t)l, 16, 0, 0);
}

// stage one K=32 chunk (4 anchors x 1KB) of this wave's 16 columns.
// sb = per-lane source base with XOR-swizzled (srow, sqs) mapping.
#define STAGE(sb, KIN, ci, slot) do {                                  \
    const unsigned short* _s = (sb) + (ci) * 32;                       \
    char* _d = myB + (slot) * 4096;                                    \
    gl_lds16(_s,             _d);                                      \
    gl_lds16(_s + (KIN),     _d + 1024);                               \
    gl_lds16(_s + 2 * (KIN), _d + 2048);                               \
    gl_lds16(_s + 3 * (KIN), _d + 3072);                               \
  } while (0)

static __device__ __forceinline__ unsigned short f2bf(float f) {
  union { float f; unsigned int u; } v; v.f = f;
  unsigned int r = v.u + 0x7fffu + ((v.u >> 16) & 1u);  // RNE
  return (unsigned short)(r >> 16);
}

// Catmull-Rom basis coeffs in ABSOLUTE anchor order (c[0..3] for anchors 0..3)
static __device__ __forceinline__ void catmull(float ph, float c[4]) {
  float t = 4.0f * ph;
  float ft = floorf(t);
  int i1 = ((int)ft) & 3;
  float w = t - ft;
  float w2 = w * w, w3 = w2 * w;
  float r0 = -0.5f * w + w2 - 0.5f * w3;
  float r1 = 1.0f - 2.5f * w2 + 1.5f * w3;
  float r2 = 0.5f * w + 2.0f * w2 - 1.5f * w3;
  float r3 = -0.5f * w2 + 0.5f * w3;
  c[(i1 + 3) & 3] = r0;
  c[i1]           = r1;
  c[(i1 + 1) & 3] = r2;
  c[(i1 + 2) & 3] = r3;
}

// ---------------------------------------------------------------------------
// Prep: transpose+convert all three weight tensors (fp32 [4K,O] -> bf16 [O,4K])
// ---------------------------------------------------------------------------
__global__ void k_wt_all(const float* __restrict__ w0, const float* __restrict__ w1,
                         const float* __restrict__ w2, unsigned short* __restrict__ t0,
                         unsigned short* __restrict__ t1, unsigned short* __restrict__ t2) {
  __shared__ float tile[32][33];
  int bid = blockIdx.x;
  const float* W; unsigned short* T; int R, C, idx;
  if (bid < 128)      { W = w0; T = t0; R = 512;  C = 256; idx = bid; }
  else if (bid < 384) { W = w1; T = t1; R = 1024; C = 256; idx = bid - 128; }
  else                { W = w2; T = t2; R = 1024; C = 128; idx = bid - 384; }
  int ntc = C >> 5;
  int tr = (idx / ntc) << 5;
  int tc = (idx % ntc) << 5;
  int tx = threadIdx.x, ty = threadIdx.y;  // (32,8)
#pragma unroll
  for (int j = ty; j < 32; j += 8)
    tile[j][tx] = W[(size_t)(tr + j) * C + (tc + tx)];
  __syncthreads();
#pragma unroll
  for (int j = ty; j < 32; j += 8)
    T[(size_t)(tc + j) * R + (tr + tx)] = f2bf(tile[tx][j]);
}

// mid-layer epilogue: bias-mix, ELU, one bf16 write per (row,col)
static __device__ __forceinline__ void epi_mid(f32x4 a0, f32x4 a1, f32x4 a2, f32x4 a3,
                                               const float bv[4], const float* cbf,
                                               int colg, int quad, char* outBuf) {
  const int g = colg >> 3;
  const int j2 = (colg & 7) * 2;
#pragma unroll
  for (int r = 0; r < 4; ++r) {
    const int m = quad * 4 + r;
    const float4 c = *(const float4*)(cbf + m * 4);
    float y = c.x * (a0[r] + bv[0]) + c.y * (a1[r] + bv[1]) +
              c.z * (a2[r] + bv[2]) + c.w * (a3[r] + bv[3]);
    float a = y > 0.0f ? y : (__expf(y) - 1.0f);  // ELU
    *(unsigned short*)(outBuf + m * 512 + (((g ^ (m & 15)) << 4) + j2)) = f2bf(a);
  }
}

#define MFMA4()                                                            \
  acc0 = __builtin_amdgcn_mfma_f32_16x16x32_bf16(av, bv0, acc0, 0, 0, 0);  \
  acc1 = __builtin_amdgcn_mfma_f32_16x16x32_bf16(av, bv1, acc1, 0, 0, 0);  \
  acc2 = __builtin_amdgcn_mfma_f32_16x16x32_bf16(av, bv2, acc2, 0, 0, 0);  \
  acc3 = __builtin_amdgcn_mfma_f32_16x16x32_bf16(av, bv3, acc3, 0, 0, 0)

#define LOADB()                                                \
  bf16x8 bv0 = *(const bf16x8*)(bs + bOff);                    \
  bf16x8 bv1 = *(const bf16x8*)(bs + 1024 + bOff);             \
  bf16x8 bv2 = *(const bf16x8*)(bs + 2048 + bOff);             \
  bf16x8 bv3 = *(const bf16x8*)(bs + 3072 + bOff)

__global__ __launch_bounds__(1024, 4) void k_fused(
    const float* __restrict__ x, const float* __restrict__ phase,
    const unsigned short* __restrict__ Wt0, const float* __restrict__ b0,
    const unsigned short* __restrict__ Wt1, const float* __restrict__ b1,
    const unsigned short* __restrict__ Wt2, const float* __restrict__ b2,
    float* __restrict__ out) {
  __shared__ __align__(1024) char smem[LDS_TOT];

  const int tid = threadIdx.x;
  const int lane = tid & 63;
  const int wid = tid >> 6;     // 0..15
  const int col = lane & 15;    // MFMA row-of-A / col-of-B lane index
  const int quad = lane >> 4;
  const int m0 = blockIdx.x * 16;
  const int colg = wid * 16 + col;           // L0/L1 output column
  const int cg = wid & 7, kh = wid >> 3;     // L2: col-group + K-half
  const int colg2 = cg * 16 + col;
  const int hi16 = (col & 12) << 4;          // A-swizzle high bits
  const int lb = (quad ^ (col & 3)) << 4;    // A-swizzle low bits

  // B chunk read offset: granule p=(col*4+quad) at XOR-swizzled position
  const int pr = col * 4 + quad;
  const int bOff = (pr ^ ((pr >> 3) & 7)) << 4;   // conflict-free ds_read_b128

  char* myB = smem + LDS_B + wid * 8192;
  float* cbf = (float*)(smem + LDS_CB);

  // per-lane staged-source: write-lane w fetches (row,qs) of p = w^((w>>3)&7)
  // (within each 4-lane group: same row, XOR-permuted quarters -> coalescing
  //  preserved; granule layout matches bOff's read swizzle)
  const int psrc = lane ^ ((lane >> 3) & 7);
  const int srow = psrc >> 2, sqs = psrc & 3;
  const unsigned short* sb0 = Wt0 + (size_t)(wid * 16 + srow) * 512 + sqs * 8;
  const unsigned short* sb1 = Wt1 + (size_t)(wid * 16 + srow) * 1024 + sqs * 8;
  const unsigned short* sb2 = Wt2 + (size_t)(cg * 16 + srow) * 1024 + kh * 128 + sqs * 8;

  // ---- issue x load first (so compiler's x-wait is counted, not vmcnt(0)) ----
  float4 xv = {0.f, 0.f, 0.f, 0.f};
  if (tid < 512)
    xv = *(const float4*)(x + (size_t)(m0 + (tid >> 5)) * 128 + (tid & 31) * 4);

  // biases (issued before the staging stream)
  float bva[4], bvb[4], bvc[4];
#pragma unroll
  for (int k = 0; k < 4; ++k) {
    bva[k] = b0[k * 256 + colg];
    bvb[k] = b1[k * 256 + colg];
    bvc[k] = b2[k * 128 + colg2];
  }

  // Catmull coeff table (16 rows)
  if (tid < 16) {
    float c[4];
    catmull(phase[m0 + tid], c);
    cbf[tid * 4 + 0] = c[0]; cbf[tid * 4 + 1] = c[1];
    cbf[tid * 4 + 2] = c[2]; cbf[tid * 4 + 3] = c[3];
  }

  // ---- prologue: stage L0 chunks 0,1 (stream stays ahead from here on) ----
  STAGE(sb0, 128, 0, 0);
  STAGE(sb0, 128, 1, 1);

  // ---- build A0: unscaled bf16 x, granule-swizzled (g ^ (row&15)) ----
  if (tid < 512) {
    const int row = tid >> 5, seg = tid & 31;
    const int g = seg >> 1, h = seg & 1;
    short4 hv;
    hv.x = (short)f2bf(xv.x); hv.y = (short)f2bf(xv.y);
    hv.z = (short)f2bf(xv.z); hv.w = (short)f2bf(xv.w);
    *(short4*)(smem + LDS_A0 + row * 256 + ((g ^ (row & 15)) << 4) + h * 8) = hv;
  }
  bar_keep_vmcnt();

  f32x4 acc0, acc1, acc2, acc3;

  // ---- layer 0: A0 (K=128 x 4 anchors) @ Wt0 -> A1 ----
  {
    acc0 = acc1 = acc2 = acc3 = (f32x4){0.f, 0.f, 0.f, 0.f};
    const char* aL = smem + LDS_A0 + col * 256 + lb;
#pragma unroll
    for (int i = 0; i < 4; ++i) {
      VMW4();
      const char* bs = myB + (i & 1) * 4096;
      bf16x8 av = *(const bf16x8*)(aL + ((i << 6) ^ hi16));
      LOADB();
      LGKM0();                       // reads in regs -> safe to overwrite slot
      if (i == 0)      STAGE(sb0, 128, 2, 0);
      else if (i == 1) STAGE(sb0, 128, 3, 1);
      else if (i == 2) STAGE(sb1, 256, 0, 0);   // cross-layer prefetch
      else             STAGE(sb1, 256, 1, 1);
      MFMA4();
    }
    epi_mid(acc0, acc1, acc2, acc3, bva, cbf, colg, quad, smem + LDS_A1);
  }
  bar_keep_vmcnt();

  // ---- layer 1: A1 (K=256 x 4 anchors) @ Wt1 -> A2 ----
  {
    acc0 = acc1 = acc2 = acc3 = (f32x4){0.f, 0.f, 0.f, 0.f};
    const char* aL = smem + LDS_A1 + col * 512 + lb;
#pragma unroll
    for (int i = 0; i < 8; ++i) {
      VMW4();
      const char* bs = myB + (i & 1) * 4096;
      bf16x8 av = *(const bf16x8*)(aL + ((i << 6) ^ hi16));
      LOADB();
      LGKM0();
      if (i < 6)       STAGE(sb1, 256, i + 2, i & 1);
      else if (i == 6) STAGE(sb2, 256, 0, 0);   // cross-layer prefetch
      else             STAGE(sb2, 256, 1, 1);
      MFMA4();
    }
    epi_mid(acc0, acc1, acc2, acc3, bvb, cbf, colg, quad, smem + LDS_A2);
  }
  bar_keep_vmcnt();

  // ---- layer 2: A2 (K=256 x 4 anchors) @ Wt2 -> out fp32 (8 colgrp x 2 kh) ----
  {
    acc0 = acc1 = acc2 = acc3 = (f32x4){0.f, 0.f, 0.f, 0.f};
    const char* aL = smem + LDS_A2 + col * 512 + kh * 256 + lb;
#pragma unroll
    for (int i = 0; i < 4; ++i) {
      if (i < 3) { VMW4(); } else { VMW0(); }
      const char* bs = myB + (i & 1) * 4096;
      bf16x8 av = *(const bf16x8*)(aL + ((i << 6) ^ hi16));
      LOADB();
      if (i < 2) {
        LGKM0();
        if (i == 0) STAGE(sb2, 256, 2, 0);
        else        STAGE(sb2, 256, 3, 1);
      }
      MFMA4();
    }

    // anchor-combine partials
    float part[4];
#pragma unroll
    for (int r = 0; r < 4; ++r) {
      const int m = quad * 4 + r;
      const float4 c = *(const float4*)(cbf + m * 4);
      part[r] = c.x * acc0[r] + c.y * acc1[r] + c.z * acc2[r] + c.w * acc3[r];
    }

    // all waves past their Bst reads -> safe to overlay reduce buffer on Bst
    bar_keep_vmcnt();
    float* red = (float*)(smem + LDS_B);   // [8][16][17] = 8704 B
    if (kh) {
#pragma unroll
      for (int r = 0; r < 4; ++r)
        red[cg * 272 + (quad * 4 + r) * 17 + col] = part[r];
    }
    bar_keep_vmcnt();
    if (!kh) {
#pragma unroll
      for (int r = 0; r < 4; ++r) {
        const int m = quad * 4 + r;
        const float4 c = *(const float4*)(cbf + m * 4);
        float y = part[r] + red[cg * 272 + m * 17 + col] +
                  c.x * bvc[0] + c.y * bvc[1] + c.z * bvc[2] + c.w * bvc[3];
        out[(size_t)(m0 + m) * 128 + colg2] = y;
      }
    }
  }
}

// ---------------------------------------------------------------------------
// ws layout: Wt0 @0 (256KB), Wt1 @256KB (512KB), Wt2 @768KB (256KB). 1 MB.
// ---------------------------------------------------------------------------
extern "C" void kernel_launch(void* const* d_in, const int* in_sizes, int n_in,
                              void* d_out, int out_size, void* d_ws, size_t ws_size,
                              hipStream_t stream) {
  const float* x     = (const float*)d_in[0];
  const float* phase = (const float*)d_in[1];
  const float* w0    = (const float*)d_in[2];
  const float* b0    = (const float*)d_in[3];
  const float* w1    = (const float*)d_in[4];
  const float* b1    = (const float*)d_in[5];
  const float* w2    = (const float*)d_in[6];
  const float* b2    = (const float*)d_in[7];
  float* out = (float*)d_out;

  char* ws = (char*)d_ws;
  unsigned short* Wt0 = (unsigned short*)ws;
  unsigned short* Wt1 = (unsigned short*)(ws + 262144);
  unsigned short* Wt2 = (unsigned short*)(ws + 262144 + 524288);

  k_wt_all<<<512, dim3(32, 8), 0, stream>>>(w0, w1, w2, Wt0, Wt1, Wt2);
  k_fused<<<256, 1024, 0, stream>>>(x, phase, Wt0, b0, Wt1, b1, Wt2, b2, out);
}

// Round 9
// 83.938 us; speedup vs baseline: 1.2317x; 1.0693x over previous
//
#include <hip/hip_runtime.h>
#include <hip/hip_bf16.h>
#include <math.h>

// PhaseMLP fused, R12: packed weight layout -> fully linear weight stream.
//   y[b,o] = sum_k c_k(b) * ( x[b,:] @ W_k + b_k )
// R11 (conflict-free LDS read) was NULL -> bank conflicts not critical.
// Rate analysis: stream runs at ~15 B/cy/CU; every gl_lds fetches 16
// scattered 64B segments (4-lane granules of 16 different rows) -> ~16K
// outstanding-limited requests/CU: 128 reqs x 64B / ~550cy = 15 B/cy.
// Fix: k_pack writes weights in the exact LDS image order: per
// (colgroup, K=32 chunk) a contiguous 4KB block [anchor][granule], where
// granule w IS the MFMA B-fragment of lane w (col=w&15, quad=w>>4).
// STAGE's gl_lds then reads 1KB CONTIGUOUS (8 full 128B lines) and the
// LDS read is dense bOff=lane*16 (conflict-free, no swizzle). Fragment
// contents bit-identical to R6/R11. k_fused skeleton = R11 (best).

typedef __attribute__((ext_vector_type(8))) short bf16x8;
typedef __attribute__((ext_vector_type(4))) float f32x4;

// LDS layout (bytes)
#define LDS_A0 0                    // 16 rows x 256B  = 4096
#define LDS_A1 4096                 // 16 rows x 512B  = 8192
#define LDS_A2 12288                // 16 rows x 512B  = 8192
#define LDS_CB 20480                // 16 x float4     = 256
#define LDS_B  21504                // 16 waves x 2 slots x 4096 = 131072
#define LDS_TOT (21504 + 131072)    // 152576 < 160K

#define VMW4()  asm volatile("s_waitcnt vmcnt(4)" ::: "memory")
#define VMW0()  asm volatile("s_waitcnt vmcnt(0)" ::: "memory")
#define LGKM0() asm volatile("s_waitcnt lgkmcnt(0)" ::: "memory")

static __device__ __forceinline__ void bar_keep_vmcnt() {
  asm volatile("s_waitcnt lgkmcnt(0)" ::: "memory");
  __builtin_amdgcn_s_barrier();
  asm volatile("" ::: "memory");
}

typedef const __attribute__((address_space(1))) unsigned char* gp1_t;
typedef __attribute__((address_space(3))) unsigned char* lp3_t;
static __device__ __forceinline__ void gl_lds16(const void* g, void* l) {
  __builtin_amdgcn_global_load_lds((gp1_t)g, (lp3_t)l, 16, 0, 0);
}

// stage one K=32 chunk (4 anchors x 1KB, all CONTIGUOUS) of this wave's
// 16 columns. sb = packed base + lane*8 shorts; chunk stride 2048 shorts.
#define STAGE(sb, ci, slot) do {                                       \
    const unsigned short* _s = (sb) + (ci) * 2048;                     \
    char* _d = myB + (slot) * 4096;                                    \
    gl_lds16(_s,        _d);                                           \
    gl_lds16(_s +  512, _d + 1024);                                    \
    gl_lds16(_s + 1024, _d + 2048);                                    \
    gl_lds16(_s + 1536, _d + 3072);                                    \
  } while (0)

static __device__ __forceinline__ unsigned short f2bf(float f) {
  union { float f; unsigned int u; } v; v.f = f;
  unsigned int r = v.u + 0x7fffu + ((v.u >> 16) & 1u);  // RNE
  return (unsigned short)(r >> 16);
}

// Catmull-Rom basis coeffs in ABSOLUTE anchor order (c[0..3] for anchors 0..3)
static __device__ __forceinline__ void catmull(float ph, float c[4]) {
  float t = 4.0f * ph;
  float ft = floorf(t);
  int i1 = ((int)ft) & 3;
  float w = t - ft;
  float w2 = w * w, w3 = w2 * w;
  float r0 = -0.5f * w + w2 - 0.5f * w3;
  float r1 = 1.0f - 2.5f * w2 + 1.5f * w3;
  float r2 = 0.5f * w + 2.0f * w2 - 1.5f * w3;
  float r3 = -0.5f * w2 + 0.5f * w3;
  c[(i1 + 3) & 3] = r0;
  c[i1]           = r1;
  c[(i1 + 1) & 3] = r2;
  c[(i1 + 2) & 3] = r3;
}

// ---------------------------------------------------------------------------
// Pack: W fp32 [4][K][O] -> bf16 packed LDS-image layout.
//   L0 (u 0..63):    [colgrp16][ci4][a4][granule64x16B]; kr=ci*32+quad*8+j
//   L1 (u 64..191):  [colgrp16][ci8][a4][granule64x16B]
//   L2 (u 192..255): [cg8*2+kh][ci4][a4][granule64x16B]; kr=kh*128+ci*32+...
// granule w = fragment of MFMA-lane w: col=w&15, quad=w>>4.
// 256 blocks x 256 threads; thread t: a=t>>6, w=t&63; writes one 16B granule.
// ---------------------------------------------------------------------------
__global__ __launch_bounds__(256) void k_pack(
    const float* __restrict__ w0, const float* __restrict__ w1,
    const float* __restrict__ w2, unsigned short* __restrict__ t0,
    unsigned short* __restrict__ t1, unsigned short* __restrict__ t2) {
  const int u = blockIdx.x;
  const int t = threadIdx.x;
  const int a = t >> 6, w = t & 63, col = w & 15, quad = w >> 4;
  const float* W; unsigned short* T; size_t dst; int kr0, oc, Ostr;
  if (u < 64) {                       // layer 0: K=128, O=256
    const int colgrp = u >> 2, ci = u & 3;
    W = w0 + (size_t)a * 128 * 256; Ostr = 256;
    kr0 = ci * 32 + quad * 8; oc = colgrp * 16 + col;
    T = t0; dst = (size_t)colgrp * 8192 + ci * 2048 + a * 512 + w * 8;
  } else if (u < 192) {               // layer 1: K=256, O=256
    const int uu = u - 64, colgrp = uu >> 3, ci = uu & 7;
    W = w1 + (size_t)a * 256 * 256; Ostr = 256;
    kr0 = ci * 32 + quad * 8; oc = colgrp * 16 + col;
    T = t1; dst = (size_t)colgrp * 16384 + ci * 2048 + a * 512 + w * 8;
  } else {                            // layer 2: K=256 (2 halves), O=128
    const int uu = u - 192, cg = uu >> 3, kh = (uu >> 2) & 1, ci = uu & 3;
    W = w2 + (size_t)a * 256 * 128; Ostr = 128;
    kr0 = kh * 128 + ci * 32 + quad * 8; oc = cg * 16 + col;
    T = t2; dst = (size_t)(cg * 2 + kh) * 8192 + ci * 2048 + a * 512 + w * 8;
  }
  bf16x8 v;
#pragma unroll
  for (int j = 0; j < 8; ++j)
    v[j] = (short)f2bf(W[(size_t)(kr0 + j) * Ostr + oc]);
  *(bf16x8*)(T + dst) = v;
}

// mid-layer epilogue: bias-mix, ELU, one bf16 write per (row,col)
static __device__ __forceinline__ void epi_mid(f32x4 a0, f32x4 a1, f32x4 a2, f32x4 a3,
                                               const float bv[4], const float* cbf,
                                               int colg, int quad, char* outBuf) {
  const int g = colg >> 3;
  const int j2 = (colg & 7) * 2;
#pragma unroll
  for (int r = 0; r < 4; ++r) {
    const int m = quad * 4 + r;
    const float4 c = *(const float4*)(cbf + m * 4);
    float y = c.x * (a0[r] + bv[0]) + c.y * (a1[r] + bv[1]) +
              c.z * (a2[r] + bv[2]) + c.w * (a3[r] + bv[3]);
    float a = y > 0.0f ? y : (__expf(y) - 1.0f);  // ELU
    *(unsigned short*)(outBuf + m * 512 + (((g ^ (m & 15)) << 4) + j2)) = f2bf(a);
  }
}

#define MFMA4()                                                            \
  acc0 = __builtin_amdgcn_mfma_f32_16x16x32_bf16(av, bv0, acc0, 0, 0, 0);  \
  acc1 = __builtin_amdgcn_mfma_f32_16x16x32_bf16(av, bv1, acc1, 0, 0, 0);  \
  acc2 = __builtin_amdgcn_mfma_f32_16x16x32_bf16(av, bv2, acc2, 0, 0, 0);  \
  acc3 = __builtin_amdgcn_mfma_f32_16x16x32_bf16(av, bv3, acc3, 0, 0, 0)

// dense fragment read: lane l reads byte l*16 of each 1KB anchor block
#define LOADB()                                                \
  bf16x8 bv0 = *(const bf16x8*)(bs + bOff);                    \
  bf16x8 bv1 = *(const bf16x8*)(bs + 1024 + bOff);             \
  bf16x8 bv2 = *(const bf16x8*)(bs + 2048 + bOff);             \
  bf16x8 bv3 = *(const bf16x8*)(bs + 3072 + bOff)

__global__ __launch_bounds__(1024, 4) void k_fused(
    const float* __restrict__ x, const float* __restrict__ phase,
    const unsigned short* __restrict__ Wt0, const float* __restrict__ b0,
    const unsigned short* __restrict__ Wt1, const float* __restrict__ b1,
    const unsigned short* __restrict__ Wt2, const float* __restrict__ b2,
    float* __restrict__ out) {
  __shared__ __align__(1024) char smem[LDS_TOT];

  const int tid = threadIdx.x;
  const int lane = tid & 63;
  const int wid = tid >> 6;     // 0..15
  const int col = lane & 15;    // MFMA row-of-A / col-of-B lane index
  const int quad = lane >> 4;
  const int m0 = blockIdx.x * 16;
  const int colg = wid * 16 + col;           // L0/L1 output column
  const int cg = wid & 7, kh = wid >> 3;     // L2: col-group + K-half
  const int colg2 = cg * 16 + col;
  const int hi16 = (col & 12) << 4;          // A-swizzle high bits
  const int lb = (quad ^ (col & 3)) << 4;    // A-swizzle low bits
  const int bOff = lane * 16;                // dense fragment read

  char* myB = smem + LDS_B + wid * 8192;
  float* cbf = (float*)(smem + LDS_CB);

  // packed per-lane source bases (shorts): base + lane*8
  const unsigned short* sb0 = Wt0 + (size_t)wid * 8192 + lane * 8;
  const unsigned short* sb1 = Wt1 + (size_t)wid * 16384 + lane * 8;
  const unsigned short* sb2 = Wt2 + (size_t)(cg * 2 + kh) * 8192 + lane * 8;

  // ---- issue x load first (so compiler's x-wait is counted, not vmcnt(0)) ----
  float4 xv = {0.f, 0.f, 0.f, 0.f};
  if (tid < 512)
    xv = *(const float4*)(x + (size_t)(m0 + (tid >> 5)) * 128 + (tid & 31) * 4);

  // biases (issued before the staging stream)
  float bva[4], bvb[4], bvc[4];
#pragma unroll
  for (int k = 0; k < 4; ++k) {
    bva[k] = b0[k * 256 + colg];
    bvb[k] = b1[k * 256 + colg];
    bvc[k] = b2[k * 128 + colg2];
  }

  // Catmull coeff table (16 rows)
  if (tid < 16) {
    float c[4];
    catmull(phase[m0 + tid], c);
    cbf[tid * 4 + 0] = c[0]; cbf[tid * 4 + 1] = c[1];
    cbf[tid * 4 + 2] = c[2]; cbf[tid * 4 + 3] = c[3];
  }

  // ---- prologue: stage L0 chunks 0,1 (stream stays ahead from here on) ----
  STAGE(sb0, 0, 0);
  STAGE(sb0, 1, 1);

  // ---- build A0: unscaled bf16 x, granule-swizzled (g ^ (row&15)) ----
  if (tid < 512) {
    const int row = tid >> 5, seg = tid & 31;
    const int g = seg >> 1, h = seg & 1;
    short4 hv;
    hv.x = (short)f2bf(xv.x); hv.y = (short)f2bf(xv.y);
    hv.z = (short)f2bf(xv.z); hv.w = (short)f2bf(xv.w);
    *(short4*)(smem + LDS_A0 + row * 256 + ((g ^ (row & 15)) << 4) + h * 8) = hv;
  }
  bar_keep_vmcnt();

  f32x4 acc0, acc1, acc2, acc3;

  // ---- layer 0: A0 (K=128 x 4 anchors) @ Wt0 -> A1 ----
  {
    acc0 = acc1 = acc2 = acc3 = (f32x4){0.f, 0.f, 0.f, 0.f};
    const char* aL = smem + LDS_A0 + col * 256 + lb;
#pragma unroll
    for (int i = 0; i < 4; ++i) {
      VMW4();
      const char* bs = myB + (i & 1) * 4096;
      bf16x8 av = *(const bf16x8*)(aL + ((i << 6) ^ hi16));
      LOADB();
      LGKM0();                       // reads in regs -> safe to overwrite slot
      if (i == 0)      STAGE(sb0, 2, 0);
      else if (i == 1) STAGE(sb0, 3, 1);
      else if (i == 2) STAGE(sb1, 0, 0);   // cross-layer prefetch
      else             STAGE(sb1, 1, 1);
      MFMA4();
    }
    epi_mid(acc0, acc1, acc2, acc3, bva, cbf, colg, quad, smem + LDS_A1);
  }
  bar_keep_vmcnt();

  // ---- layer 1: A1 (K=256 x 4 anchors) @ Wt1 -> A2 ----
  {
    acc0 = acc1 = acc2 = acc3 = (f32x4){0.f, 0.f, 0.f, 0.f};
    const char* aL = smem + LDS_A1 + col * 512 + lb;
#pragma unroll
    for (int i = 0; i < 8; ++i) {
      VMW4();
      const char* bs = myB + (i & 1) * 4096;
      bf16x8 av = *(const bf16x8*)(aL + ((i << 6) ^ hi16));
      LOADB();
      LGKM0();
      if (i < 6)       STAGE(sb1, i + 2, i & 1);
      else if (i == 6) STAGE(sb2, 0, 0);   // cross-layer prefetch
      else             STAGE(sb2, 1, 1);
      MFMA4();
    }
    epi_mid(acc0, acc1, acc2, acc3, bvb, cbf, colg, quad, smem + LDS_A2);
  }
  bar_keep_vmcnt();

  // ---- layer 2: A2 (K=256 x 4 anchors) @ Wt2 -> out fp32 (8 colgrp x 2 kh) ----
  {
    acc0 = acc1 = acc2 = acc3 = (f32x4){0.f, 0.f, 0.f, 0.f};
    const char* aL = smem + LDS_A2 + col * 512 + kh * 256 + lb;
#pragma unroll
    for (int i = 0; i < 4; ++i) {
      if (i < 3) { VMW4(); } else { VMW0(); }
      const char* bs = myB + (i & 1) * 4096;
      bf16x8 av = *(const bf16x8*)(aL + ((i << 6) ^ hi16));
      LOADB();
      if (i < 2) {
        LGKM0();
        if (i == 0) STAGE(sb2, 2, 0);
        else        STAGE(sb2, 3, 1);
      }
      MFMA4();
    }

    // anchor-combine partials
    float part[4];
#pragma unroll
    for (int r = 0; r < 4; ++r) {
      const int m = quad * 4 + r;
      const float4 c = *(const float4*)(cbf + m * 4);
      part[r] = c.x * acc0[r] + c.y * acc1[r] + c.z * acc2[r] + c.w * acc3[r];
    }

    // all waves past their Bst reads -> safe to overlay reduce buffer on Bst
    bar_keep_vmcnt();
    float* red = (float*)(smem + LDS_B);   // [8][16][17] = 8704 B
    if (kh) {
#pragma unroll
      for (int r = 0; r < 4; ++r)
        red[cg * 272 + (quad * 4 + r) * 17 + col] = part[r];
    }
    bar_keep_vmcnt();
    if (!kh) {
#pragma unroll
      for (int r = 0; r < 4; ++r) {
        const int m = quad * 4 + r;
        const float4 c = *(const float4*)(cbf + m * 4);
        float y = part[r] + red[cg * 272 + m * 17 + col] +
                  c.x * bvc[0] + c.y * bvc[1] + c.z * bvc[2] + c.w * bvc[3];
        out[(size_t)(m0 + m) * 128 + colg2] = y;
      }
    }
  }
}

// ---------------------------------------------------------------------------
// ws layout: Wt0 @0 (256KB), Wt1 @256KB (512KB), Wt2 @768KB (256KB). 1 MB.
// ---------------------------------------------------------------------------
extern "C" void kernel_launch(void* const* d_in, const int* in_sizes, int n_in,
                              void* d_out, int out_size, void* d_ws, size_t ws_size,
                              hipStream_t stream) {
  const float* x     = (const float*)d_in[0];
  const float* phase = (const float*)d_in[1];
  const float* w0    = (const float*)d_in[2];
  const float* b0    = (const float*)d_in[3];
  const float* w1    = (const float*)d_in[4];
  const float* b1    = (const float*)d_in[5];
  const float* w2    = (const float*)d_in[6];
  const float* b2    = (const float*)d_in[7];
  float* out = (float*)d_out;

  char* ws = (char*)d_ws;
  unsigned short* Wt0 = (unsigned short*)ws;
  unsigned short* Wt1 = (unsigned short*)(ws + 262144);
  unsigned short* Wt2 = (unsigned short*)(ws + 262144 + 524288);

  k_pack<<<256, 256, 0, stream>>>(w0, w1, w2, Wt0, Wt1, Wt2);
  k_fused<<<256, 1024, 0, stream>>>(x, phase, Wt0, b0, Wt1, b1, Wt2, b2, out);
}

// Round 10
// 83.074 us; speedup vs baseline: 1.2445x; 1.0104x over previous
//
#include <hip/hip_runtime.h>
#include <hip/hip_bf16.h>
#include <math.h>

// PhaseMLP fused, R13: R12 k_fused (best, byte-identical) + coalesced k_pack.
//   y[b,o] = sum_k c_k(b) * ( x[b,:] @ W_k + b_k )
// R12 post-mortem: packed linear weight stream won -5.8us (request-
// fragmentation theory confirmed). k_fused untouched this round.
// R13 change: k_pack had the same fragmentation disease on its READ side
// (8 strided fp32 loads/thread = 16 scattered 64B segments per wave-instr).
// v2: 64 blocks, each owns a [4a][32k][64o] fp32 tile; phase 1 = fully
// coalesced float4 loads into pad-66 LDS (2-way bank aliasing = free);
// phase 2 = gather 8-k column slices from LDS, f2bf, write 16B granules
// (wave writes 1KB contiguous). Same granule mapping as R12 -> k_fused
// input bit-identical -> absmax unchanged (0.0625).

typedef __attribute__((ext_vector_type(8))) short bf16x8;
typedef __attribute__((ext_vector_type(4))) float f32x4;

// LDS layout (bytes) for k_fused
#define LDS_A0 0                    // 16 rows x 256B  = 4096
#define LDS_A1 4096                 // 16 rows x 512B  = 8192
#define LDS_A2 12288                // 16 rows x 512B  = 8192
#define LDS_CB 20480                // 16 x float4     = 256
#define LDS_B  21504                // 16 waves x 2 slots x 4096 = 131072
#define LDS_TOT (21504 + 131072)    // 152576 < 160K

#define VMW4()  asm volatile("s_waitcnt vmcnt(4)" ::: "memory")
#define VMW0()  asm volatile("s_waitcnt vmcnt(0)" ::: "memory")
#define LGKM0() asm volatile("s_waitcnt lgkmcnt(0)" ::: "memory")

static __device__ __forceinline__ void bar_keep_vmcnt() {
  asm volatile("s_waitcnt lgkmcnt(0)" ::: "memory");
  __builtin_amdgcn_s_barrier();
  asm volatile("" ::: "memory");
}

typedef const __attribute__((address_space(1))) unsigned char* gp1_t;
typedef __attribute__((address_space(3))) unsigned char* lp3_t;
static __device__ __forceinline__ void gl_lds16(const void* g, void* l) {
  __builtin_amdgcn_global_load_lds((gp1_t)g, (lp3_t)l, 16, 0, 0);
}

// stage one K=32 chunk (4 anchors x 1KB, all CONTIGUOUS) of this wave's
// 16 columns. sb = packed base + lane*8 shorts; chunk stride 2048 shorts.
#define STAGE(sb, ci, slot) do {                                       \
    const unsigned short* _s = (sb) + (ci) * 2048;                     \
    char* _d = myB + (slot) * 4096;                                    \
    gl_lds16(_s,        _d);                                           \
    gl_lds16(_s +  512, _d + 1024);                                    \
    gl_lds16(_s + 1024, _d + 2048);                                    \
    gl_lds16(_s + 1536, _d + 3072);                                    \
  } while (0)

static __device__ __forceinline__ unsigned short f2bf(float f) {
  union { float f; unsigned int u; } v; v.f = f;
  unsigned int r = v.u + 0x7fffu + ((v.u >> 16) & 1u);  // RNE
  return (unsigned short)(r >> 16);
}

// Catmull-Rom basis coeffs in ABSOLUTE anchor order (c[0..3] for anchors 0..3)
static __device__ __forceinline__ void catmull(float ph, float c[4]) {
  float t = 4.0f * ph;
  float ft = floorf(t);
  int i1 = ((int)ft) & 3;
  float w = t - ft;
  float w2 = w * w, w3 = w2 * w;
  float r0 = -0.5f * w + w2 - 0.5f * w3;
  float r1 = 1.0f - 2.5f * w2 + 1.5f * w3;
  float r2 = 0.5f * w + 2.0f * w2 - 1.5f * w3;
  float r3 = -0.5f * w2 + 0.5f * w3;
  c[(i1 + 3) & 3] = r0;
  c[i1]           = r1;
  c[(i1 + 1) & 3] = r2;
  c[(i1 + 2) & 3] = r3;
}

// ---------------------------------------------------------------------------
// Pack v2 (coalesced): W fp32 [4][K][O] -> bf16 packed LDS-image layout.
// 64 blocks x 256 threads. Block unit = (layer, q = 64-col group, ci8/ci4).
//   u  0..15 : L0 (K=128,O=256): q=u>>2 (0..3), ci=u&3
//   u 16..47 : L1 (K=256,O=256): uu=u-16, q=uu>>3 (0..3), ci8=uu&7
//   u 48..63 : L2 (K=256,O=128): uu=u-48, q=uu>>3 (0..1), ci8=uu&7
// Phase 1: load [4a][32k][64o] fp32 tile, fully coalesced float4, into
//          LDS tile pad-66 (2-way bank aliasing only).
// Phase 2: thread (a=t>>6, w=t&63; col=w&15, quad=w>>4) loops s=0..3
//          sub-colgroups: gathers k=quad*8+j (j=0..7) at col s*16+col,
//          writes granule (16B) -> wave writes 1KB contiguous.
// Granule mapping identical to R12's k_pack.
// ---------------------------------------------------------------------------
#define TPAD 66
__global__ __launch_bounds__(256) void k_pack(
    const float* __restrict__ w0, const float* __restrict__ w1,
    const float* __restrict__ w2, unsigned short* __restrict__ t0,
    unsigned short* __restrict__ t1, unsigned short* __restrict__ t2) {
  __shared__ float tile[4 * 32 * TPAD];   // 33792 B
  const int u = blockIdx.x;
  const int t = threadIdx.x;

  const float* W; unsigned short* T;
  int q, ci8, KO, Ostr, nsub, cgmul, cgstride, cisub;
  if (u < 16) {            // layer 0
    q = u >> 2; ci8 = u & 3;
    W = w0; T = t0; KO = 128 * 256; Ostr = 256; nsub = 4;
    cgmul = 8192; cgstride = 1; cisub = ci8;         // dst: g*8192 + ci*2048
  } else if (u < 48) {     // layer 1
    const int uu = u - 16; q = uu >> 3; ci8 = uu & 7;
    W = w1; T = t1; KO = 256 * 256; Ostr = 256; nsub = 4;
    cgmul = 16384; cgstride = 1; cisub = ci8;        // dst: g*16384 + ci8*2048
  } else {                 // layer 2
    const int uu = u - 48; q = uu >> 3; ci8 = uu & 7;
    W = w2; T = t2; KO = 256 * 128; Ostr = 128; nsub = 4;
    // dst: (cg*2+kh)*8192 + ci4*2048 ; cg = q*4+s, kh = ci8>>2, ci4 = ci8&3
    cgmul = 16384; cgstride = 2; cisub = ci8;        // handled below
  }
  const int kbase = ci8 * 32;        // absolute k row base (ci8*32 == kh*128+ci4*32)
  const int obase = q * 64;

  // ---- phase 1: coalesced load, 8 x float4 per thread ----
#pragma unroll
  for (int p = 0; p < 8; ++p) {
    const int f4 = p * 256 + t;              // 0..2047
    const int a = f4 >> 9;                   // 0..3
    const int k = (f4 >> 4) & 31;            // 0..31
    const int o4 = f4 & 15;                  // 0..15
    const float4 v = *(const float4*)(W + (size_t)a * KO +
                                      (size_t)(kbase + k) * Ostr + obase + o4 * 4);
    float* d = tile + a * (32 * TPAD) + k * TPAD + o4 * 4;
    d[0] = v.x; d[1] = v.y; d[2] = v.z; d[3] = v.w;
  }
  __syncthreads();

  // ---- phase 2: gather + convert + contiguous granule writes ----
  const int a = t >> 6, w = t & 63, col = w & 15, quad = w >> 4;
#pragma unroll
  for (int s = 0; s < nsub; ++s) {
    const float* src = tile + a * (32 * TPAD) + (quad * 8) * TPAD + s * 16 + col;
    bf16x8 v;
#pragma unroll
    for (int j = 0; j < 8; ++j) v[j] = (short)f2bf(src[j * TPAD]);
    size_t dst;
    if (u < 48) {
      dst = (size_t)(q * 4 + s) * (size_t)cgmul + (size_t)cisub * 2048 + a * 512 + w * 8;
    } else {
      const int cg = q * 4 + s, kh = ci8 >> 2, ci4 = ci8 & 3;
      dst = (size_t)(cg * 2 + kh) * 8192 + (size_t)ci4 * 2048 + a * 512 + w * 8;
    }
    *(bf16x8*)(T + dst) = v;
  }
}

// mid-layer epilogue: bias-mix, ELU, one bf16 write per (row,col)
static __device__ __forceinline__ void epi_mid(f32x4 a0, f32x4 a1, f32x4 a2, f32x4 a3,
                                               const float bv[4], const float* cbf,
                                               int colg, int quad, char* outBuf) {
  const int g = colg >> 3;
  const int j2 = (colg & 7) * 2;
#pragma unroll
  for (int r = 0; r < 4; ++r) {
    const int m = quad * 4 + r;
    const float4 c = *(const float4*)(cbf + m * 4);
    float y = c.x * (a0[r] + bv[0]) + c.y * (a1[r] + bv[1]) +
              c.z * (a2[r] + bv[2]) + c.w * (a3[r] + bv[3]);
    float a = y > 0.0f ? y : (__expf(y) - 1.0f);  // ELU
    *(unsigned short*)(outBuf + m * 512 + (((g ^ (m & 15)) << 4) + j2)) = f2bf(a);
  }
}

#define MFMA4()                                                            \
  acc0 = __builtin_amdgcn_mfma_f32_16x16x32_bf16(av, bv0, acc0, 0, 0, 0);  \
  acc1 = __builtin_amdgcn_mfma_f32_16x16x32_bf16(av, bv1, acc1, 0, 0, 0);  \
  acc2 = __builtin_amdgcn_mfma_f32_16x16x32_bf16(av, bv2, acc2, 0, 0, 0);  \
  acc3 = __builtin_amdgcn_mfma_f32_16x16x32_bf16(av, bv3, acc3, 0, 0, 0)

// dense fragment read: lane l reads byte l*16 of each 1KB anchor block
#define LOADB()                                                \
  bf16x8 bv0 = *(const bf16x8*)(bs + bOff);                    \
  bf16x8 bv1 = *(const bf16x8*)(bs + 1024 + bOff);             \
  bf16x8 bv2 = *(const bf16x8*)(bs + 2048 + bOff);             \
  bf16x8 bv3 = *(const bf16x8*)(bs + 3072 + bOff)

__global__ __launch_bounds__(1024, 4) void k_fused(
    const float* __restrict__ x, const float* __restrict__ phase,
    const unsigned short* __restrict__ Wt0, const float* __restrict__ b0,
    const unsigned short* __restrict__ Wt1, const float* __restrict__ b1,
    const unsigned short* __restrict__ Wt2, const float* __restrict__ b2,
    float* __restrict__ out) {
  __shared__ __align__(1024) char smem[LDS_TOT];

  const int tid = threadIdx.x;
  const int lane = tid & 63;
  const int wid = tid >> 6;     // 0..15
  const int col = lane & 15;    // MFMA row-of-A / col-of-B lane index
  const int quad = lane >> 4;
  const int m0 = blockIdx.x * 16;
  const int colg = wid * 16 + col;           // L0/L1 output column
  const int cg = wid & 7, kh = wid >> 3;     // L2: col-group + K-half
  const int colg2 = cg * 16 + col;
  const int hi16 = (col & 12) << 4;          // A-swizzle high bits
  const int lb = (quad ^ (col & 3)) << 4;    // A-swizzle low bits
  const int bOff = lane * 16;                // dense fragment read

  char* myB = smem + LDS_B + wid * 8192;
  float* cbf = (float*)(smem + LDS_CB);

  // packed per-lane source bases (shorts): base + lane*8
  const unsigned short* sb0 = Wt0 + (size_t)wid * 8192 + lane * 8;
  const unsigned short* sb1 = Wt1 + (size_t)wid * 16384 + lane * 8;
  const unsigned short* sb2 = Wt2 + (size_t)(cg * 2 + kh) * 8192 + lane * 8;

  // ---- issue x load first (so compiler's x-wait is counted, not vmcnt(0)) ----
  float4 xv = {0.f, 0.f, 0.f, 0.f};
  if (tid < 512)
    xv = *(const float4*)(x + (size_t)(m0 + (tid >> 5)) * 128 + (tid & 31) * 4);

  // biases (issued before the staging stream)
  float bva[4], bvb[4], bvc[4];
#pragma unroll
  for (int k = 0; k < 4; ++k) {
    bva[k] = b0[k * 256 + colg];
    bvb[k] = b1[k * 256 + colg];
    bvc[k] = b2[k * 128 + colg2];
  }

  // Catmull coeff table (16 rows)
  if (tid < 16) {
    float c[4];
    catmull(phase[m0 + tid], c);
    cbf[tid * 4 + 0] = c[0]; cbf[tid * 4 + 1] = c[1];
    cbf[tid * 4 + 2] = c[2]; cbf[tid * 4 + 3] = c[3];
  }

  // ---- prologue: stage L0 chunks 0,1 (stream stays ahead from here on) ----
  STAGE(sb0, 0, 0);
  STAGE(sb0, 1, 1);

  // ---- build A0: unscaled bf16 x, granule-swizzled (g ^ (row&15)) ----
  if (tid < 512) {
    const int row = tid >> 5, seg = tid & 31;
    const int g = seg >> 1, h = seg & 1;
    short4 hv;
    hv.x = (short)f2bf(xv.x); hv.y = (short)f2bf(xv.y);
    hv.z = (short)f2bf(xv.z); hv.w = (short)f2bf(xv.w);
    *(short4*)(smem + LDS_A0 + row * 256 + ((g ^ (row & 15)) << 4) + h * 8) = hv;
  }
  bar_keep_vmcnt();

  f32x4 acc0, acc1, acc2, acc3;

  // ---- layer 0: A0 (K=128 x 4 anchors) @ Wt0 -> A1 ----
  {
    acc0 = acc1 = acc2 = acc3 = (f32x4){0.f, 0.f, 0.f, 0.f};
    const char* aL = smem + LDS_A0 + col * 256 + lb;
#pragma unroll
    for (int i = 0; i < 4; ++i) {
      VMW4();
      const char* bs = myB + (i & 1) * 4096;
      bf16x8 av = *(const bf16x8*)(aL + ((i << 6) ^ hi16));
      LOADB();
      LGKM0();                       // reads in regs -> safe to overwrite slot
      if (i == 0)      STAGE(sb0, 2, 0);
      else if (i == 1) STAGE(sb0, 3, 1);
      else if (i == 2) STAGE(sb1, 0, 0);   // cross-layer prefetch
      else             STAGE(sb1, 1, 1);
      MFMA4();
    }
    epi_mid(acc0, acc1, acc2, acc3, bva, cbf, colg, quad, smem + LDS_A1);
  }
  bar_keep_vmcnt();

  // ---- layer 1: A1 (K=256 x 4 anchors) @ Wt1 -> A2 ----
  {
    acc0 = acc1 = acc2 = acc3 = (f32x4){0.f, 0.f, 0.f, 0.f};
    const char* aL = smem + LDS_A1 + col * 512 + lb;
#pragma unroll
    for (int i = 0; i < 8; ++i) {
      VMW4();
      const char* bs = myB + (i & 1) * 4096;
      bf16x8 av = *(const bf16x8*)(aL + ((i << 6) ^ hi16));
      LOADB();
      LGKM0();
      if (i < 6)       STAGE(sb1, i + 2, i & 1);
      else if (i == 6) STAGE(sb2, 0, 0);   // cross-layer prefetch
      else             STAGE(sb2, 1, 1);
      MFMA4();
    }
    epi_mid(acc0, acc1, acc2, acc3, bvb, cbf, colg, quad, smem + LDS_A2);
  }
  bar_keep_vmcnt();

  // ---- layer 2: A2 (K=256 x 4 anchors) @ Wt2 -> out fp32 (8 colgrp x 2 kh) ----
  {
    acc0 = acc1 = acc2 = acc3 = (f32x4){0.f, 0.f, 0.f, 0.f};
    const char* aL = smem + LDS_A2 + col * 512 + kh * 256 + lb;
#pragma unroll
    for (int i = 0; i < 4; ++i) {
      if (i < 3) { VMW4(); } else { VMW0(); }
      const char* bs = myB + (i & 1) * 4096;
      bf16x8 av = *(const bf16x8*)(aL + ((i << 6) ^ hi16));
      LOADB();
      if (i < 2) {
        LGKM0();
        if (i == 0) STAGE(sb2, 2, 0);
        else        STAGE(sb2, 3, 1);
      }
      MFMA4();
    }

    // anchor-combine partials
    float part[4];
#pragma unroll
    for (int r = 0; r < 4; ++r) {
      const int m = quad * 4 + r;
      const float4 c = *(const float4*)(cbf + m * 4);
      part[r] = c.x * acc0[r] + c.y * acc1[r] + c.z * acc2[r] + c.w * acc3[r];
    }

    // all waves past their Bst reads -> safe to overlay reduce buffer on Bst
    bar_keep_vmcnt();
    float* red = (float*)(smem + LDS_B);   // [8][16][17] = 8704 B
    if (kh) {
#pragma unroll
      for (int r = 0; r < 4; ++r)
        red[cg * 272 + (quad * 4 + r) * 17 + col] = part[r];
    }
    bar_keep_vmcnt();
    if (!kh) {
#pragma unroll
      for (int r = 0; r < 4; ++r) {
        const int m = quad * 4 + r;
        const float4 c = *(const float4*)(cbf + m * 4);
        float y = part[r] + red[cg * 272 + m * 17 + col] +
                  c.x * bvc[0] + c.y * bvc[1] + c.z * bvc[2] + c.w * bvc[3];
        out[(size_t)(m0 + m) * 128 + colg2] = y;
      }
    }
  }
}

// ---------------------------------------------------------------------------
// ws layout: Wt0 @0 (256KB), Wt1 @256KB (512KB), Wt2 @768KB (256KB). 1 MB.
// ---------------------------------------------------------------------------
extern "C" void kernel_launch(void* const* d_in, const int* in_sizes, int n_in,
                              void* d_out, int out_size, void* d_ws, size_t ws_size,
                              hipStream_t stream) {
  const float* x     = (const float*)d_in[0];
  const float* phase = (const float*)d_in[1];
  const float* w0    = (const float*)d_in[2];
  const float* b0    = (const float*)d_in[3];
  const float* w1    = (const float*)d_in[4];
  const float* b1    = (const float*)d_in[5];
  const float* w2    = (const float*)d_in[6];
  const float* b2    = (const float*)d_in[7];
  float* out = (float*)d_out;

  char* ws = (char*)d_ws;
  unsigned short* Wt0 = (unsigned short*)ws;
  unsigned short* Wt1 = (unsigned short*)(ws + 262144);
  unsigned short* Wt2 = (unsigned short*)(ws + 262144 + 524288);

  k_pack<<<64, 256, 0, stream>>>(w0, w1, w2, Wt0, Wt1, Wt2);
  k_fused<<<256, 1024, 0, stream>>>(x, phase, Wt0, b0, Wt1, b1, Wt2, b2, out);
}

// Round 11
// 82.927 us; speedup vs baseline: 1.2467x; 1.0018x over previous
//
#include <hip/hip_runtime.h>
#include <hip/hip_bf16.h>
#include <math.h>

// PhaseMLP fused, R14: packed weights + REGISTER-direct B (no LDS round-trip).
//   y[b,o] = sum_k c_k(b) * ( x[b,:] @ W_k + b_k )
// R13 post-mortem: with the stream linearized (R12), the tall pole is the
// B LDS round-trip: the LDS port carries 1MB DMA-in + 1MB ds_read-out +
// 0.3MB A traffic (~8-11us, banks shared). R9's reg-direct failure (40us)
// was confounded: its loads were the scattered 16x64B pattern. With the
// PACKED layout a reg-direct B load is base+chunk*4096+anchor*1024+lane*16
// = linear 1KB/wave-instruction (same request structure as gl_lds) and B
// never touches LDS. Depth-3 rotating pre[3][4] (48 VGPR, 12 loads in
// flight/wave); no vmcnt/lgkm asm in the loop (compiler scoreboard);
// raw s_barrier+lgkmcnt(0) at layer bounds keeps loads live across layers.
// LDS = A+cb+red only (29.5KB). Chunk/accum order identical to R13.

typedef __attribute__((ext_vector_type(8))) short bf16x8;
typedef __attribute__((ext_vector_type(4))) float f32x4;

// LDS layout (bytes) for k_fused
#define LDS_A0  0                   // 16 rows x 256B = 4096
#define LDS_A1  4096                // 16 rows x 512B = 8192
#define LDS_A2  12288               // 16 rows x 512B = 8192
#define LDS_CB  20480               // 16 x float4    = 256
#define LDS_RED 20736               // [8][16][17] fp32 = 8704
#define LDS_TOT (20736 + 8704)      // 29440

static __device__ __forceinline__ void bar_lgkm() {
  asm volatile("s_waitcnt lgkmcnt(0)" ::: "memory");
  __builtin_amdgcn_s_barrier();
  asm volatile("" ::: "memory");
}

static __device__ __forceinline__ unsigned short f2bf(float f) {
  union { float f; unsigned int u; } v; v.f = f;
  unsigned int r = v.u + 0x7fffu + ((v.u >> 16) & 1u);  // RNE
  return (unsigned short)(r >> 16);
}

// Catmull-Rom basis coeffs in ABSOLUTE anchor order (c[0..3] for anchors 0..3)
static __device__ __forceinline__ void catmull(float ph, float c[4]) {
  float t = 4.0f * ph;
  float ft = floorf(t);
  int i1 = ((int)ft) & 3;
  float w = t - ft;
  float w2 = w * w, w3 = w2 * w;
  float r0 = -0.5f * w + w2 - 0.5f * w3;
  float r1 = 1.0f - 2.5f * w2 + 1.5f * w3;
  float r2 = 0.5f * w + 2.0f * w2 - 1.5f * w3;
  float r3 = -0.5f * w2 + 0.5f * w3;
  c[(i1 + 3) & 3] = r0;
  c[i1]           = r1;
  c[(i1 + 1) & 3] = r2;
  c[(i1 + 2) & 3] = r3;
}

// ---------------------------------------------------------------------------
// Pack v2 (coalesced, unchanged from R13): W fp32 [4][K][O] -> bf16 packed
// LDS-image layout; granule w = MFMA B-fragment of lane w (col=w&15,q=w>>4).
// ---------------------------------------------------------------------------
#define TPAD 66
__global__ __launch_bounds__(256) void k_pack(
    const float* __restrict__ w0, const float* __restrict__ w1,
    const float* __restrict__ w2, unsigned short* __restrict__ t0,
    unsigned short* __restrict__ t1, unsigned short* __restrict__ t2) {
  __shared__ float tile[4 * 32 * TPAD];   // 33792 B
  const int u = blockIdx.x;
  const int t = threadIdx.x;

  const float* W; unsigned short* T;
  int q, ci8, KO, Ostr, nsub, cgmul, cisub;
  if (u < 16) {            // layer 0
    q = u >> 2; ci8 = u & 3;
    W = w0; T = t0; KO = 128 * 256; Ostr = 256; nsub = 4;
    cgmul = 8192; cisub = ci8;
  } else if (u < 48) {     // layer 1
    const int uu = u - 16; q = uu >> 3; ci8 = uu & 7;
    W = w1; T = t1; KO = 256 * 256; Ostr = 256; nsub = 4;
    cgmul = 16384; cisub = ci8;
  } else {                 // layer 2
    const int uu = u - 48; q = uu >> 3; ci8 = uu & 7;
    W = w2; T = t2; KO = 256 * 128; Ostr = 128; nsub = 4;
    cgmul = 16384; cisub = ci8;
  }
  const int kbase = ci8 * 32;
  const int obase = q * 64;

  // ---- phase 1: coalesced load, 8 x float4 per thread ----
#pragma unroll
  for (int p = 0; p < 8; ++p) {
    const int f4 = p * 256 + t;              // 0..2047
    const int a = f4 >> 9;                   // 0..3
    const int k = (f4 >> 4) & 31;            // 0..31
    const int o4 = f4 & 15;                  // 0..15
    const float4 v = *(const float4*)(W + (size_t)a * KO +
                                      (size_t)(kbase + k) * Ostr + obase + o4 * 4);
    float* d = tile + a * (32 * TPAD) + k * TPAD + o4 * 4;
    d[0] = v.x; d[1] = v.y; d[2] = v.z; d[3] = v.w;
  }
  __syncthreads();

  // ---- phase 2: gather + convert + contiguous granule writes ----
  const int a = t >> 6, w = t & 63, col = w & 15, quad = w >> 4;
#pragma unroll
  for (int s = 0; s < nsub; ++s) {
    const float* src = tile + a * (32 * TPAD) + (quad * 8) * TPAD + s * 16 + col;
    bf16x8 v;
#pragma unroll
    for (int j = 0; j < 8; ++j) v[j] = (short)f2bf(src[j * TPAD]);
    size_t dst;
    if (u < 48) {
      dst = (size_t)(q * 4 + s) * (size_t)cgmul + (size_t)cisub * 2048 + a * 512 + w * 8;
    } else {
      const int cg = q * 4 + s, kh = ci8 >> 2, ci4 = ci8 & 3;
      dst = (size_t)(cg * 2 + kh) * 8192 + (size_t)ci4 * 2048 + a * 512 + w * 8;
    }
    *(bf16x8*)(T + dst) = v;
  }
}

// mid-layer epilogue: bias-mix, ELU, one bf16 write per (row,col)
static __device__ __forceinline__ void epi_mid(f32x4 a0, f32x4 a1, f32x4 a2, f32x4 a3,
                                               const float bv[4], const float* cbf,
                                               int colg, int quad, char* outBuf) {
  const int g = colg >> 3;
  const int j2 = (colg & 7) * 2;
#pragma unroll
  for (int r = 0; r < 4; ++r) {
    const int m = quad * 4 + r;
    const float4 c = *(const float4*)(cbf + m * 4);
    float y = c.x * (a0[r] + bv[0]) + c.y * (a1[r] + bv[1]) +
              c.z * (a2[r] + bv[2]) + c.w * (a3[r] + bv[3]);
    float a = y > 0.0f ? y : (__expf(y) - 1.0f);  // ELU
    *(unsigned short*)(outBuf + m * 512 + (((g ^ (m & 15)) << 4) + j2)) = f2bf(a);
  }
}

// load one packed K=32 chunk (4 anchors x 1KB contiguous) into rotating slot.
// sb already includes lane*8 shorts; wave-level each load = 1KB linear.
#define LOADCH(sb, ci, sl) do {                                        \
    pre[sl][0] = *(const bf16x8*)((sb) + (ci) * 2048);                 \
    pre[sl][1] = *(const bf16x8*)((sb) + (ci) * 2048 + 512);           \
    pre[sl][2] = *(const bf16x8*)((sb) + (ci) * 2048 + 1024);          \
    pre[sl][3] = *(const bf16x8*)((sb) + (ci) * 2048 + 1536);          \
  } while (0)

// global chunk id c: 0..3 = L0, 4..11 = L1, 12..15 = L2 (compile-time folds)
#define ISSUE(c, sl) do {                                              \
    if ((c) < 4)       LOADCH(sb0, (c), sl);                           \
    else if ((c) < 12) LOADCH(sb1, (c) - 4, sl);                       \
    else if ((c) < 16) LOADCH(sb2, (c) - 12, sl);                      \
  } while (0)

#define MFMA4()                                                            \
  acc0 = __builtin_amdgcn_mfma_f32_16x16x32_bf16(av, bv0, acc0, 0, 0, 0);  \
  acc1 = __builtin_amdgcn_mfma_f32_16x16x32_bf16(av, bv1, acc1, 0, 0, 0);  \
  acc2 = __builtin_amdgcn_mfma_f32_16x16x32_bf16(av, bv2, acc2, 0, 0, 0);  \
  acc3 = __builtin_amdgcn_mfma_f32_16x16x32_bf16(av, bv3, acc3, 0, 0, 0)

__global__ __launch_bounds__(1024, 4) void k_fused(
    const float* __restrict__ x, const float* __restrict__ phase,
    const unsigned short* __restrict__ Wt0, const float* __restrict__ b0,
    const unsigned short* __restrict__ Wt1, const float* __restrict__ b1,
    const unsigned short* __restrict__ Wt2, const float* __restrict__ b2,
    float* __restrict__ out) {
  __shared__ __align__(1024) char smem[LDS_TOT];

  const int tid = threadIdx.x;
  const int lane = tid & 63;
  const int wid = tid >> 6;     // 0..15
  const int col = lane & 15;    // MFMA row-of-A / col-of-B lane index
  const int quad = lane >> 4;
  const int m0 = blockIdx.x * 16;
  const int colg = wid * 16 + col;           // L0/L1 output column
  const int cg = wid & 7, kh = wid >> 3;     // L2: col-group + K-half
  const int colg2 = cg * 16 + col;
  const int hi16 = (col & 12) << 4;          // A-swizzle high bits
  const int lb = (quad ^ (col & 3)) << 4;    // A-swizzle low bits

  float* cbf = (float*)(smem + LDS_CB);

  // packed per-lane source bases (shorts): base + lane*8
  const unsigned short* sb0 = Wt0 + (size_t)wid * 8192 + lane * 8;
  const unsigned short* sb1 = Wt1 + (size_t)wid * 16384 + lane * 8;
  const unsigned short* sb2 = Wt2 + (size_t)(cg * 2 + kh) * 8192 + lane * 8;

  // ---- prologue global loads ----
  float4 xv = {0.f, 0.f, 0.f, 0.f};
  if (tid < 512)
    xv = *(const float4*)(x + (size_t)(m0 + (tid >> 5)) * 128 + (tid & 31) * 4);

  float bva[4], bvb[4], bvc[4];
#pragma unroll
  for (int k = 0; k < 4; ++k) {
    bva[k] = b0[k * 256 + colg];
    bvb[k] = b1[k * 256 + colg];
    bvc[k] = b2[k * 128 + colg2];
  }

  // ---- start the register B pipeline: chunks 0..2 -> slots 0..2 ----
  bf16x8 pre[3][4];
  LOADCH(sb0, 0, 0);
  LOADCH(sb0, 1, 1);
  LOADCH(sb0, 2, 2);

  // Catmull coeff table (16 rows)
  if (tid < 16) {
    float c[4];
    catmull(phase[m0 + tid], c);
    cbf[tid * 4 + 0] = c[0]; cbf[tid * 4 + 1] = c[1];
    cbf[tid * 4 + 2] = c[2]; cbf[tid * 4 + 3] = c[3];
  }

  // ---- build A0: unscaled bf16 x, granule-swizzled (g ^ (row&15)) ----
  if (tid < 512) {
    const int row = tid >> 5, seg = tid & 31;
    const int g = seg >> 1, h = seg & 1;
    short4 hv;
    hv.x = (short)f2bf(xv.x); hv.y = (short)f2bf(xv.y);
    hv.z = (short)f2bf(xv.z); hv.w = (short)f2bf(xv.w);
    *(short4*)(smem + LDS_A0 + row * 256 + ((g ^ (row & 15)) << 4) + h * 8) = hv;
  }
  bar_lgkm();

  f32x4 acc0, acc1, acc2, acc3;

  // ---- layer 0: A0 (K=128 x 4 anchors) @ Wt0 -> A1. steps s=0..3 ----
  {
    acc0 = acc1 = acc2 = acc3 = (f32x4){0.f, 0.f, 0.f, 0.f};
    const char* aL = smem + LDS_A0 + col * 256 + lb;
#pragma unroll
    for (int i = 0; i < 4; ++i) {
      const int sl = i % 3;
      bf16x8 bv0 = pre[sl][0], bv1 = pre[sl][1],
             bv2 = pre[sl][2], bv3 = pre[sl][3];
      ISSUE(i + 3, sl);
      bf16x8 av = *(const bf16x8*)(aL + ((i << 6) ^ hi16));
      MFMA4();
    }
    epi_mid(acc0, acc1, acc2, acc3, bva, cbf, colg, quad, smem + LDS_A1);
  }
  bar_lgkm();

  // ---- layer 1: A1 (K=256 x 4 anchors) @ Wt1 -> A2. steps s=4..11 ----
  {
    acc0 = acc1 = acc2 = acc3 = (f32x4){0.f, 0.f, 0.f, 0.f};
    const char* aL = smem + LDS_A1 + col * 512 + lb;
#pragma unroll
    for (int i = 0; i < 8; ++i) {
      const int s = i + 4;
      const int sl = s % 3;
      bf16x8 bv0 = pre[sl][0], bv1 = pre[sl][1],
             bv2 = pre[sl][2], bv3 = pre[sl][3];
      ISSUE(s + 3, sl);
      bf16x8 av = *(const bf16x8*)(aL + ((i << 6) ^ hi16));
      MFMA4();
    }
    epi_mid(acc0, acc1, acc2, acc3, bvb, cbf, colg, quad, smem + LDS_A2);
  }
  bar_lgkm();

  // ---- layer 2: A2 (K=256 x 4 anchors) @ Wt2 -> out. steps s=12..15 ----
  {
    acc0 = acc1 = acc2 = acc3 = (f32x4){0.f, 0.f, 0.f, 0.f};
    const char* aL = smem + LDS_A2 + col * 512 + kh * 256 + lb;
#pragma unroll
    for (int i = 0; i < 4; ++i) {
      const int s = i + 12;
      const int sl = s % 3;
      bf16x8 bv0 = pre[sl][0], bv1 = pre[sl][1],
             bv2 = pre[sl][2], bv3 = pre[sl][3];
      ISSUE(s + 3, sl);    // s+3 = 15 only at i=0; guards fold away the rest
      bf16x8 av = *(const bf16x8*)(aL + ((i << 6) ^ hi16));
      MFMA4();
    }

    // anchor-combine partials
    float part[4];
#pragma unroll
    for (int r = 0; r < 4; ++r) {
      const int m = quad * 4 + r;
      const float4 c = *(const float4*)(cbf + m * 4);
      part[r] = c.x * acc0[r] + c.y * acc1[r] + c.z * acc2[r] + c.w * acc3[r];
    }

    float* red = (float*)(smem + LDS_RED);   // [8][16][17]
    if (kh) {
#pragma unroll
      for (int r = 0; r < 4; ++r)
        red[cg * 272 + (quad * 4 + r) * 17 + col] = part[r];
    }
    bar_lgkm();
    if (!kh) {
#pragma unroll
      for (int r = 0; r < 4; ++r) {
        const int m = quad * 4 + r;
        const float4 c = *(const float4*)(cbf + m * 4);
        float y = part[r] + red[cg * 272 + m * 17 + col] +
                  c.x * bvc[0] + c.y * bvc[1] + c.z * bvc[2] + c.w * bvc[3];
        out[(size_t)(m0 + m) * 128 + colg2] = y;
      }
    }
  }
}

// ---------------------------------------------------------------------------
// ws layout: Wt0 @0 (256KB), Wt1 @256KB (512KB), Wt2 @768KB (256KB). 1 MB.
// ---------------------------------------------------------------------------
extern "C" void kernel_launch(void* const* d_in, const int* in_sizes, int n_in,
                              void* d_out, int out_size, void* d_ws, size_t ws_size,
                              hipStream_t stream) {
  const float* x     = (const float*)d_in[0];
  const float* phase = (const float*)d_in[1];
  const float* w0    = (const float*)d_in[2];
  const float* b0    = (const float*)d_in[3];
  const float* w1    = (const float*)d_in[4];
  const float* b1    = (const float*)d_in[5];
  const float* w2    = (const float*)d_in[6];
  const float* b2    = (const float*)d_in[7];
  float* out = (float*)d_out;

  char* ws = (char*)d_ws;
  unsigned short* Wt0 = (unsigned short*)ws;
  unsigned short* Wt1 = (unsigned short*)(ws + 262144);
  unsigned short* Wt2 = (unsigned short*)(ws + 262144 + 524288);

  k_pack<<<64, 256, 0, stream>>>(w0, w1, w2, Wt0, Wt1, Wt2);
  k_fused<<<256, 1024, 0, stream>>>(x, phase, Wt0, b0, Wt1, b1, Wt2, b2, out);
}